// Round 12
// baseline (1519.691 us; speedup 1.0000x reference)
//
#include <hip/hip_runtime.h>
#include <hip/hip_bf16.h>
#include <hip/hip_cooperative_groups.h>
#include <math.h>

namespace cg = cooperative_groups;

#define H 768
#define S 1024
#define BATCH 2
#define T 2048  // BATCH*S
#define TH ((size_t)T * H)
#define NO nullptr

typedef unsigned short u16;
typedef unsigned long long u64;
typedef __attribute__((ext_vector_type(8))) short short8;
typedef __attribute__((ext_vector_type(4))) float f32x4;

__device__ __forceinline__ u16 f2b(float f) {
  __hip_bfloat16 h = __float2bfloat16(f);
  return *reinterpret_cast<u16*>(&h);
}
__device__ __forceinline__ float b2f(u16 u) {
  __hip_bfloat16 h = *reinterpret_cast<__hip_bfloat16*>(&u);
  return __bfloat162float(h);
}
__device__ __forceinline__ void gload16(const u16* g, u16* lds) {
  __builtin_amdgcn_global_load_lds((const __attribute__((address_space(1))) void*)g,
                                   (__attribute__((address_space(3))) void*)lds, 16, 0, 0);
}

// ======================= fused prep: weight transpose + x/y cvt + meany stage1 ===========
struct WprepArgs {
  const float* src[14];
  unsigned dst[14];
  int ktiles[14];
  int tstart[15];
  const float *x, *y;
  u16 *bx, *by;
  float* part;
};
__global__ __launch_bounds__(256) void prep_k(WprepArgs a, u16* __restrict__ wt) {
  __shared__ float sT[64][68];
  int blk = blockIdx.x;
  int t = threadIdx.x;
  int ts = a.tstart[14];
  if (blk >= ts + 1536) {  // meany1: 48 blocks
    int bb = blk - ts - 1536;
    int b = bb / 24, r = bb % 24, cc = r / 8, sc = r % 8;
    int c = cc * 256 + t;
    const float* yp = a.y + (size_t)b * S * H + (size_t)sc * 128 * H + c;
    float s = 0.f;
    for (int j = 0; j < 128; ++j) s += yp[(size_t)j * H];
    a.part[(sc * 2 + b) * H + c] = s;
    return;
  }
  if (blk >= ts) {  // cvt: 1536 blocks (768 x, 768 y)
    int bb = blk - ts;
    const float* src = (bb < 768) ? a.x : a.y;
    u16* dst = (bb < 768) ? a.bx : a.by;
    int i = (bb % 768) * 256 + t;
    float4 va = ((const float4*)src)[2 * i];
    float4 vb = ((const float4*)src)[2 * i + 1];
    u16 tmp[8] = {f2b(va.x), f2b(va.y), f2b(va.z), f2b(va.w), f2b(vb.x), f2b(vb.y), f2b(vb.z), f2b(vb.w)};
    ((uint4*)dst)[i] = *(uint4*)tmp;
    return;
  }
  int mi = 0;
  while (blk >= a.tstart[mi + 1]) ++mi;
  int local = blk - a.tstart[mi];
  int kt = a.ktiles[mi];
  int tn = local / kt, tk = local % kt;
  int K = kt * 64;
  const float* W = a.src[mi];
  u16* D = wt + a.dst[mi];
  int r = t >> 2, c = (t & 3) * 16;
  const float4* srcp = (const float4*)(W + ((size_t)(tk * 64 + r)) * H + tn * 64 + c);
  float4 v0 = srcp[0], v1 = srcp[1], v2 = srcp[2], v3 = srcp[3];
  *(float4*)&sT[r][c] = v0; *(float4*)&sT[r][c + 4] = v1;
  *(float4*)&sT[r][c + 8] = v2; *(float4*)&sT[r][c + 12] = v3;
  __syncthreads();
  int n = t >> 2, kk = (t & 3) * 16;
  u16 tmp[16];
  #pragma unroll
  for (int j = 0; j < 16; ++j) tmp[j] = f2b(sT[kk + j][n]);
  uint4* dst = (uint4*)(D + ((size_t)(tn * 64 + n)) * K + tk * 64 + kk);
  dst[0] = *(uint4*)&tmp[0];
  dst[1] = *(uint4*)&tmp[8];
}

// ======================= wave-per-output GEMV (fallback path) =======================
__global__ __launch_bounds__(256) void gemv_k(const float* __restrict__ A, const float* __restrict__ W,
                                              const float* __restrict__ bias, float* __restrict__ O, int act) {
  int gid = blockIdx.x * 4 + (threadIdx.x >> 6);
  int lane = threadIdx.x & 63;
  int b = gid / H, n = gid % H;
  const float* a = A + b * H;
  float s = 0.f;
  #pragma unroll
  for (int i = 0; i < 12; ++i) {
    int k = lane + 64 * i;
    s = fmaf(a[k], W[(size_t)k * H + n], s);
  }
  #pragma unroll
  for (int off = 32; off; off >>= 1) s += __shfl_xor(s, off);
  if (lane == 0) {
    if (bias) s += bias[n];
    if (act) s = tanhf(s);
    O[gid] = s;
  }
}

// ======================= multi-region bf16 MFMA GEMM (+ meany2 aux blocks) =======================
struct Reg {
  const u16 *A, *W, *A2, *W2;
  const float *bias, *perbatch;
  u16* Cb; u16* CbT; float* Cf; float* colPart;
  int ldw, ldw2;
};
struct GArgs {
  Reg r0, r1, r2; int act;
  int nx;                    // main x-blocks; x >= nx are aux
  const float* m2part; float* m2ybar;  // aux: meany2
};

__global__ __launch_bounds__(512) void bgemm_k(GArgs ga) {
  __shared__ u16 sA[3][64 * 64];
  __shared__ u16 sB[3][64 * 64];
  int t = threadIdx.x;
  if ((int)blockIdx.x >= ga.nx) {  // aux: meany2 (3 blocks x 512 thr, y==0 only)
    if (blockIdx.y == 0 && ga.m2part) {
      int idx = ((int)blockIdx.x - ga.nx) * 512 + t;
      int b = idx / H, c = idx % H;
      float s = 0.f;
      #pragma unroll
      for (int sc = 0; sc < 8; ++sc) s += ga.m2part[(sc * 2 + b) * H + c];
      ga.m2ybar[idx] = s * (1.0f / 1024.0f);
    }
    return;
  }
  int ri = blockIdx.x / 12;
  Reg R;
  if (ri == 0) R = ga.r0; else if (ri == 1) R = ga.r1; else R = ga.r2;
  int n0 = (blockIdx.x % 12) * 64;
  int m0 = blockIdx.y * 64;
  int w = t >> 6, l = t & 63, lr = l & 15, lg = l >> 4;
  int wr = (w & 3) * 16, wc = (w >> 2) * 32;

  f32x4 acc[2];
  acc[0] = (f32x4){0.f, 0.f, 0.f, 0.f};
  acc[1] = (f32x4){0.f, 0.f, 0.f, 0.f};

  int NT = R.A2 ? 24 : 12;

  auto stage = [&](int ti) {
    int bi = ti % 3;
    const u16* Aq = (ti < 12) ? R.A : R.A2;
    const u16* Wq = (ti < 12) ? R.W : R.W2;
    int ldwq = (ti < 12) ? R.ldw : R.ldw2;
    int k0 = (ti % 12) * 64;
    int rr = t >> 3, c8 = t & 7;
    gload16(Aq + (size_t)(m0 + rr) * H + k0 + 8 * (c8 ^ (rr & 7)), &sA[bi][0] + t * 8);
    gload16(Wq + (size_t)(n0 + rr) * ldwq + k0 + 8 * (c8 ^ (rr & 7)), &sB[bi][0] + t * 8);
  };

  stage(0);
  stage(1);
  for (int kt = 0; kt < NT; ++kt) {
    if (kt + 1 < NT) asm volatile("s_waitcnt vmcnt(2)" ::: "memory");
    else             asm volatile("s_waitcnt vmcnt(0)" ::: "memory");
    __builtin_amdgcn_s_barrier();
    if (kt + 2 < NT) stage(kt + 2);
    const u16* sAv = &sA[kt % 3][0];
    const u16* sBv = &sB[kt % 3][0];
    __builtin_amdgcn_s_setprio(1);
    #pragma unroll
    for (int kh = 0; kh < 2; ++kh) {
      int arow = wr + lr;
      short8 af = *(const short8*)(sAv + arow * 64 + 8 * ((4 * kh + lg) ^ (arow & 7)));
      #pragma unroll
      for (int ni = 0; ni < 2; ++ni) {
        int brow = wc + 16 * ni + lr;
        short8 bf = *(const short8*)(sBv + brow * 64 + 8 * ((4 * kh + lg) ^ (brow & 7)));
        acc[ni] = __builtin_amdgcn_mfma_f32_16x16x32_bf16(af, bf, acc[ni], 0, 0, 0);
      }
    }
    __builtin_amdgcn_s_setprio(0);
  }

  float ps[2] = {0.f, 0.f};
  #pragma unroll
  for (int ni = 0; ni < 2; ++ni) {
    int col = n0 + wc + 16 * ni + lr;
    u16 tmp4[4];
    #pragma unroll
    for (int reg = 0; reg < 4; ++reg) {
      int row = m0 + wr + lg * 4 + reg;
      int bb = row >> 10;
      float v = acc[ni][reg];
      if (R.bias) v += R.bias[col];
      if (R.perbatch) v += R.perbatch[bb * H + col];
      if (ga.act) v = tanhf(v);
      tmp4[reg] = f2b(v);
      if (R.Cb) R.Cb[(size_t)row * H + col] = tmp4[reg];
      if (R.Cf) R.Cf[(size_t)row * H + col] = v;
      if (R.colPart) ps[ni] += __expf(b2f(tmp4[reg]));
    }
    if (R.CbT) {
      int row0 = m0 + wr + lg * 4;
      int bb = row0 >> 10, tok = row0 & 1023, hh = col >> 6, dd = col & 63;
      *(u64*)&R.CbT[((size_t)((bb * 12 + hh) * 64 + dd)) * 1024 + tok] = *(u64*)tmp4;
    }
  }
  if (R.colPart) {
    #pragma unroll
    for (int ni = 0; ni < 2; ++ni) {
      float p = ps[ni];
      p += __shfl_xor(p, 16);
      p += __shfl_xor(p, 32);
      if (lg == 0) {
        int col = n0 + wc + 16 * ni + lr;
        R.colPart[(size_t)(blockIdx.y * 4 + (w & 3)) * H + col] = p;
      }
    }
  }
}

// ======================= MFMA attention (+ gemv aux blocks >= 384) ==========
__global__ __launch_bounds__(256) void mattn_k(
    const u16* __restrict__ Q, const u16* __restrict__ Kg,
    const u16* __restrict__ VT, u16* __restrict__ O,
    const float* __restrict__ gA, const float* __restrict__ gW,
    const float* __restrict__ gBias, float* __restrict__ gO)
{
  __shared__ u16 sK[3][64 * 64];
  __shared__ u16 sV[3][64 * 64];
  __shared__ u16 sQ[64 * 64];
  __shared__ u16 sP[4 * 16 * 64];
  int t = threadIdx.x;
  if ((int)blockIdx.x >= 384) {  // aux: gemv (ybar @ dv_w + dv_b -> dvbar)
    int gid = ((int)blockIdx.x - 384) * 4 + (t >> 6);
    int lane = t & 63;
    int b = gid / H, n = gid % H;
    const float* av = gA + b * H;
    float s = 0.f;
    #pragma unroll
    for (int i = 0; i < 12; ++i) {
      int k = lane + 64 * i;
      s = fmaf(av[k], gW[(size_t)k * H + n], s);
    }
    #pragma unroll
    for (int off = 32; off; off >>= 1) s += __shfl_xor(s, off);
    if (lane == 0) gO[gid] = s + gBias[n];
    return;
  }
  int w = t >> 6, l = t & 63, lr = l & 15, lg = l >> 4;
  int blk = blockIdx.x;
  int b = blk / 192; int rem = blk % 192; int h = rem / 16; int q0 = (rem % 16) * 64;

  #pragma unroll
  for (int i = 0; i < 2; ++i) {
    int id = t + i * 256; int r = id >> 3, c = id & 7;
    uint4 v = *(const uint4*)(Q + ((size_t)(b * 1024 + q0 + r)) * H + h * 64 + 8 * c);
    *(uint4*)(&sQ[0] + r * 64 + 8 * (c ^ (r & 7))) = v;
  }

  auto stageKV = [&](int ti) {
    int bi = ti % 3;
    int kv0 = ti * 64;
    #pragma unroll
    for (int ii = 0; ii < 2; ++ii) {
      int chunk = w * 128 + ii * 64 + l;
      int rr = chunk >> 3, c8 = chunk & 7;
      gload16(Kg + ((size_t)(b * 1024 + kv0 + rr)) * H + h * 64 + 8 * (c8 ^ (rr & 7)),
              &sK[bi][0] + (w * 128 + ii * 64) * 8);
      gload16(VT + ((size_t)((b * 12 + h) * 64 + rr)) * 1024 + kv0 + 8 * (c8 ^ (rr & 7)),
              &sV[bi][0] + (w * 128 + ii * 64) * 8);
    }
  };

  stageKV(0);
  stageKV(1);
  asm volatile("s_waitcnt lgkmcnt(0)" ::: "memory");
  __builtin_amdgcn_s_barrier();
  short8 qreg[2];
  #pragma unroll
  for (int kh = 0; kh < 2; ++kh) {
    int qrow = 16 * w + lr;
    qreg[kh] = *(const short8*)(&sQ[0] + qrow * 64 + 8 * ((4 * kh + lg) ^ (qrow & 7)));
  }

  f32x4 oacc[4];
  #pragma unroll
  for (int i = 0; i < 4; ++i) oacc[i] = (f32x4){0.f, 0.f, 0.f, 0.f};
  float lsum = 0.f;

  for (int kt = 0; kt < 16; ++kt) {
    if (kt + 1 < 16) asm volatile("s_waitcnt vmcnt(4)" ::: "memory");
    else             asm volatile("s_waitcnt vmcnt(0)" ::: "memory");
    __builtin_amdgcn_s_barrier();
    if (kt + 2 < 16) stageKV(kt + 2);
    const u16* sKv = &sK[kt % 3][0];
    const u16* sVv = &sV[kt % 3][0];

    f32x4 sacc[4];
    #pragma unroll
    for (int i = 0; i < 4; ++i) sacc[i] = (f32x4){0.f, 0.f, 0.f, 0.f};
    __builtin_amdgcn_s_setprio(1);
    #pragma unroll
    for (int kh = 0; kh < 2; ++kh) {
      #pragma unroll
      for (int ns = 0; ns < 4; ++ns) {
        int krow = 16 * ns + lr;
        short8 kf = *(const short8*)(sKv + krow * 64 + 8 * ((4 * kh + lg) ^ (krow & 7)));
        sacc[ns] = __builtin_amdgcn_mfma_f32_16x16x32_bf16(kf, qreg[kh], sacc[ns], 0, 0, 0);
      }
    }
    __builtin_amdgcn_s_setprio(0);

    #pragma unroll
    for (int ns = 0; ns < 4; ++ns) {
      u16 t4[4];
      #pragma unroll
      for (int reg = 0; reg < 4; ++reg) {
        float p = __expf(sacc[ns][reg] * 0.125f);
        lsum += p;
        t4[reg] = f2b(p);
      }
      unsigned byteoff = (unsigned)(w * 2048 + lr * 128 + (((16 * ns + lg * 4) * 2) ^ ((lr & 7) << 4)));
      *(u64*)((char*)sP + byteoff) = *(u64*)t4;
    }

    __builtin_amdgcn_s_setprio(1);
    #pragma unroll
    for (int kh = 0; kh < 2; ++kh) {
      short8 pf = *(const short8*)((char*)sP + w * 2048 + lr * 128 + (((4 * kh + lg) << 4) ^ ((lr & 7) << 4)));
      #pragma unroll
      for (int ds = 0; ds < 4; ++ds) {
        int vrow = 16 * ds + lr;
        short8 vf = *(const short8*)(sVv + vrow * 64 + 8 * ((4 * kh + lg) ^ (vrow & 7)));
        oacc[ds] = __builtin_amdgcn_mfma_f32_16x16x32_bf16(pf, vf, oacc[ds], 0, 0, 0);
      }
    }
    __builtin_amdgcn_s_setprio(0);
  }

  lsum += __shfl_xor(lsum, 16);
  lsum += __shfl_xor(lsum, 32);
  float linv = 1.0f / lsum;
  #pragma unroll
  for (int r = 0; r < 4; ++r) {
    float inv = __shfl(linv, lg * 4 + r);
    int qrow = q0 + 16 * w + lg * 4 + r;
    #pragma unroll
    for (int ds = 0; ds < 4; ++ds) {
      int d = 16 * ds + lr;
      O[((size_t)(b * 1024 + qrow)) * H + h * 64 + d] = f2b(oacc[ds][r] * inv);
    }
  }
}

// ======================= axis-1 softmax apply (fallback path) ===========
__global__ __launch_bounds__(256) void colsmA_k(
    const u16* __restrict__ Z, const float* __restrict__ part,
    const float* __restrict__ mulvec, const u16* __restrict__ mulmat, u16* __restrict__ O) {
  int blk = blockIdx.x;
  int b = blk >> 7, sc = blk & 127;
  int t = threadIdx.x;
  float s0 = 0.f, s1 = 0.f, s2 = 0.f;
  for (int i = b * 64; i < b * 64 + 64; ++i) {
    const float* pp = part + (size_t)i * H;
    s0 += pp[t]; s1 += pp[t + 256]; s2 += pp[t + 512];
  }
  float i0 = 1.0f / s0, i1 = 1.0f / s1, i2 = 1.0f / s2;
  size_t base = ((size_t)(b * 1024 + sc * 8)) * H;
  float m0 = 0.f, m1 = 0.f, m2 = 0.f;
  if (mulvec) { m0 = mulvec[b * H + t]; m1 = mulvec[b * H + t + 256]; m2 = mulvec[b * H + t + 512]; }
  #pragma unroll
  for (int j = 0; j < 8; ++j) {
    size_t row = base + (size_t)j * H;
    float e0 = __expf(b2f(Z[row + t]));
    float e1 = __expf(b2f(Z[row + t + 256]));
    float e2 = __expf(b2f(Z[row + t + 512]));
    float u0 = mulmat ? b2f(mulmat[row + t]) : m0;
    float u1 = mulmat ? b2f(mulmat[row + t + 256]) : m1;
    float u2 = mulmat ? b2f(mulmat[row + t + 512]) : m2;
    O[row + t] = f2b(u0 * e0 * i0);
    O[row + t + 256] = f2b(u1 * e1 * i1);
    O[row + t + 512] = f2b(u2 * e2 * i2);
  }
}

// ======================= gate + fusion (fallback path) =======================
__global__ __launch_bounds__(256) void gatefuse_k(
    const u16* __restrict__ DF, const u16* __restrict__ VF,
    const float* __restrict__ GW, u16* __restrict__ FU)
{
  __shared__ float red[256];
  int tok = blockIdx.x;
  int t = threadIdx.x;
  const u16* df = DF + (size_t)tok * H;
  const u16* vf = VF + (size_t)tok * H;
  float dv[3], vv[3];
  float p = 0.f;
  #pragma unroll
  for (int i = 0; i < 3; ++i) {
    int c = t + i * 256;
    dv[i] = b2f(df[c]); vv[i] = b2f(vf[c]);
    p = fmaf(dv[i], GW[c], p);
    p = fmaf(vv[i], GW[H + c], p);
  }
  red[t] = p; __syncthreads();
  for (int st = 128; st; st >>= 1) { if (t < st) red[t] += red[t + st]; __syncthreads(); }
  float g = 1.0f / (1.0f + __expf(-red[0]));
  u16* fu = FU + (size_t)tok * H;
  #pragma unroll
  for (int i = 0; i < 3; ++i) {
    int c = t + i * 256;
    fu[c] = f2b(g * vv[i] + (1.0f - g) * dv[i]);
  }
}

// ======================= nf + final output (fallback path) =======================
__global__ __launch_bounds__(256) void nffinal_k(
    const u16* __restrict__ VAN, const float* __restrict__ NP,
    const float* __restrict__ NW, const float* __restrict__ FP,
    float* __restrict__ OUT)
{
  __shared__ float red[256];
  int tok = blockIdx.x;
  int t = threadIdx.x;
  const u16* va = VAN + (size_t)tok * H;
  const float* np = NP + (size_t)tok * H;
  float p = 0.f;
  #pragma unroll
  for (int i = 0; i < 3; ++i) {
    int c = t + i * 256;
    p = fmaf(b2f(va[c]), NW[c], p);
    p = fmaf(np[c], NW[H + c], p);
  }
  red[t] = p; __syncthreads();
  for (int st = 128; st; st >>= 1) { if (t < st) red[t] += red[t + st]; __syncthreads(); }
  float nf = 1.0f / (1.0f + __expf(-red[0]));
  const float* fp = FP + (size_t)tok * H;
  float* o = OUT + (size_t)tok * H;
  #pragma unroll
  for (int i = 0; i < 3; ++i) {
    int c = t + i * 256;
    o[c] = nf * tanhf(fp[c]);
  }
}

// ======================= cooperative mega-kernel =======================
struct TileW {
  const u16 *A, *W, *A2, *W2;
  const float *bias, *perbatch;
  u16* Cb; float* Cf; float* colPart;
  int ldw, ldw2, act;
};

__device__ __forceinline__ void gemm_tile(u16* sAb, u16* sBb, const TileW& R, int tile) {
  int t = threadIdx.x;
  int n0 = (tile % 12) * 64;
  int m0 = (tile / 12) * 64;
  int w = t >> 6, l = t & 63, lr = l & 15, lg = l >> 4;
  int wr = (w & 3) * 16, wc = (w >> 2) * 32;
  f32x4 acc[2];
  acc[0] = (f32x4){0.f, 0.f, 0.f, 0.f};
  acc[1] = (f32x4){0.f, 0.f, 0.f, 0.f};
  int NT = R.A2 ? 24 : 12;
  auto stage = [&](int ti) {
    int bi = ti % 3;
    const u16* Aq = (ti < 12) ? R.A : R.A2;
    const u16* Wq = (ti < 12) ? R.W : R.W2;
    int ldwq = (ti < 12) ? R.ldw : R.ldw2;
    int k0 = (ti % 12) * 64;
    int rr = t >> 3, c8 = t & 7;
    gload16(Aq + (size_t)(m0 + rr) * H + k0 + 8 * (c8 ^ (rr & 7)), sAb + bi * 4096 + t * 8);
    gload16(Wq + (size_t)(n0 + rr) * ldwq + k0 + 8 * (c8 ^ (rr & 7)), sBb + bi * 4096 + t * 8);
  };
  stage(0);
  stage(1);
  for (int kt = 0; kt < NT; ++kt) {
    if (kt + 1 < NT) asm volatile("s_waitcnt vmcnt(2)" ::: "memory");
    else             asm volatile("s_waitcnt vmcnt(0)" ::: "memory");
    __builtin_amdgcn_s_barrier();
    if (kt + 2 < NT) stage(kt + 2);
    const u16* sAv = sAb + (kt % 3) * 4096;
    const u16* sBv = sBb + (kt % 3) * 4096;
    __builtin_amdgcn_s_setprio(1);
    #pragma unroll
    for (int kh = 0; kh < 2; ++kh) {
      int arow = wr + lr;
      short8 af = *(const short8*)(sAv + arow * 64 + 8 * ((4 * kh + lg) ^ (arow & 7)));
      #pragma unroll
      for (int ni = 0; ni < 2; ++ni) {
        int brow = wc + 16 * ni + lr;
        short8 bf = *(const short8*)(sBv + brow * 64 + 8 * ((4 * kh + lg) ^ (brow & 7)));
        acc[ni] = __builtin_amdgcn_mfma_f32_16x16x32_bf16(af, bf, acc[ni], 0, 0, 0);
      }
    }
    __builtin_amdgcn_s_setprio(0);
  }
  float ps[2] = {0.f, 0.f};
  #pragma unroll
  for (int ni = 0; ni < 2; ++ni) {
    int col = n0 + wc + 16 * ni + lr;
    u16 tmp4[4];
    #pragma unroll
    for (int reg = 0; reg < 4; ++reg) {
      int row = m0 + wr + lg * 4 + reg;
      int bb = row >> 10;
      float v = acc[ni][reg];
      if (R.bias) v += R.bias[col];
      if (R.perbatch) v += R.perbatch[bb * H + col];
      if (R.act) v = tanhf(v);
      tmp4[reg] = f2b(v);
      if (R.Cb) R.Cb[(size_t)row * H + col] = tmp4[reg];
      if (R.Cf) R.Cf[(size_t)row * H + col] = v;
      if (R.colPart) ps[ni] += __expf(b2f(tmp4[reg]));
    }
  }
  if (R.colPart) {
    #pragma unroll
    for (int ni = 0; ni < 2; ++ni) {
      float p = ps[ni];
      p += __shfl_xor(p, 16);
      p += __shfl_xor(p, 32);
      if (lg == 0) {
        int col = n0 + wc + 16 * ni + lr;
        R.colPart[(size_t)((tile / 12) * 4 + (w & 3)) * H + col] = p;
      }
    }
  }
}

struct MegaArgs {
  const u16* bVan;
  u16 *bX, *bY, *bQ, *bK, *bV;
  float *F0, *F1, *out;
  const u16 *w_vanfc, *w_WV, *w_dth2, *w_difffc, *w_diffout2, *w_vg, *w_vg2,
            *w_vanout, *w_vanout2, *w_difffus, *w_vanfus, *w_nf, *w_final;
  const float *b_vanfc, *b_difffc, *b_vanout, *b_difffus, *b_vanfus, *b_nf, *b_final;
  const float *dvbar;
  const float *gate_w, *nf_out_w;
  const float *g2A, *g2W, *g2B;  // gemv2: dvbar @ diff_out_w(top) + diff_out_b -> c2
  float *c2;
  float *colp, *cinv;
};

__global__ __launch_bounds__(512, 4) void mega_k(MegaArgs a) {
  __shared__ u16 sA[3 * 4096];
  __shared__ u16 sB[3 * 4096];
  float* red = (float*)sA;  // reuse for token reductions
  cg::grid_group grid = cg::this_grid();
  int blk = blockIdx.x;    // 0..383
  int t = threadIdx.x;     // 0..511

  // ---- P1: gemv2 (c2) on blocks<192 + tv (bVan@vanfc->bX) + gA (bVan@WV->bK) ----
  if (blk < 192) {
    int gid = blk * 8 + (t >> 6);
    int lane = t & 63;
    int b = gid / H, n = gid % H;
    const float* av = a.g2A + b * H;
    float s = 0.f;
    #pragma unroll
    for (int i = 0; i < 12; ++i) {
      int k = lane + 64 * i;
      s = fmaf(av[k], a.g2W[(size_t)k * H + n], s);
    }
    #pragma unroll
    for (int off = 32; off; off >>= 1) s += __shfl_xor(s, off);
    if (lane == 0) a.c2[gid] = s + a.g2B[n];
  }
  {
    TileW r1 = {a.bVan, a.w_vanfc, NO, NO, a.b_vanfc, NO, a.bX, NO, NO, H, 0, 1};
    gemm_tile(sA, sB, r1, blk);
    TileW r2 = {a.bVan, a.w_WV, NO, NO, NO, NO, a.bK, NO, NO, H, 0, 1};
    gemm_tile(sA, sB, r2, blk);
  }
  __threadfence(); grid.sync();

  // ---- P2: z1 = tv @ dth2 -> bY (+colPart) ----
  {
    TileW r = {a.bX, a.w_dth2, NO, NO, NO, NO, a.bY, NO, a.colp, 2 * H, 0, 0};
    gemm_tile(sA, sB, r, blk);
  }
  __threadfence(); grid.sync();

  // ---- P3: inv1 ----
  if (blk < 3) {
    int idx = blk * 512 + t;
    int b = idx / H, c = idx % H;
    float s = 0.f;
    for (int i = b * 64; i < b * 64 + 64; ++i) s += a.colp[(size_t)i * H + c];
    a.cinv[idx] = 1.0f / s;
  }
  __threadfence(); grid.sync();

  // ---- P4: d_theta = dvbar * softmax(z1) -> bQ ----
  for (int row = blk; row < 2048; row += 384) {
    int b = row >> 10;
    size_t rb = (size_t)row * H;
    int c0 = t;
    a.bQ[rb + c0] = f2b(a.dvbar[b * H + c0] * __expf(b2f(a.bY[rb + c0])) * a.cinv[b * H + c0]);
    if (t < 256) {
      int c1 = t + 512;
      a.bQ[rb + c1] = f2b(a.dvbar[b * H + c1] * __expf(b2f(a.bY[rb + c1])) * a.cinv[b * H + c1]);
    }
  }
  __threadfence(); grid.sync();

  // ---- P5: gB -> bV ; diff_out -> bY ----
  {
    TileW r1 = {a.bQ, a.w_difffc, NO, NO, a.b_difffc, NO, a.bV, NO, NO, H, 0, 1};
    gemm_tile(sA, sB, r1, blk);
    TileW r2 = {a.bQ, a.w_diffout2, NO, NO, NO, a.c2, a.bY, NO, NO, 2 * H, 0, 1};
    gemm_tile(sA, sB, r2, blk);
  }
  __threadfence(); grid.sync();

  // ---- P6: z2 = gA@vg1 + gB@vg2 -> bX (+colPart) ----
  {
    TileW r = {a.bK, a.w_vg, a.bV, a.w_vg2, NO, NO, a.bX, NO, a.colp, 2 * H, 2 * H, 0};
    gemm_tile(sA, sB, r, blk);
  }
  __threadfence(); grid.sync();

  // ---- P7: inv2 ----
  if (blk < 3) {
    int idx = blk * 512 + t;
    int b = idx / H, c = idx % H;
    float s = 0.f;
    for (int i = b * 64; i < b * 64 + 64; ++i) s += a.colp[(size_t)i * H + c];
    a.cinv[idx] = 1.0f / s;
  }
  __threadfence(); grid.sync();

  // ---- P8: a_gamma = van * softmax(z2) -> bX (in place) ----
  for (int row = blk; row < 2048; row += 384) {
    int b = row >> 10;
    size_t rb = (size_t)row * H;
    int c0 = t;
    a.bX[rb + c0] = f2b(b2f(a.bVan[rb + c0]) * __expf(b2f(a.bX[rb + c0])) * a.cinv[b * H + c0]);
    if (t < 256) {
      int c1 = t + 512;
      a.bX[rb + c1] = f2b(b2f(a.bVan[rb + c1]) * __expf(b2f(a.bX[rb + c1])) * a.cinv[b * H + c1]);
    }
  }
  __threadfence(); grid.sync();

  // ---- P9: van_out (dual) -> bK ; diff_fusion -> bQ ----
  {
    TileW r1 = {a.bVan, a.w_vanout, a.bX, a.w_vanout2, a.b_vanout, NO, a.bK, NO, NO, 2 * H, 2 * H, 1};
    gemm_tile(sA, sB, r1, blk);
    TileW r2 = {a.bY, a.w_difffus, NO, NO, a.b_difffus, NO, a.bQ, NO, NO, H, 0, 1};
    gemm_tile(sA, sB, r2, blk);
  }
  __threadfence(); grid.sync();

  // ---- P10: van_fusion -> bV ----
  {
    TileW r = {a.bK, a.w_vanfus, NO, NO, a.b_vanfus, NO, a.bV, NO, NO, H, 0, 1};
    gemm_tile(sA, sB, r, blk);
  }
  __threadfence(); grid.sync();

  // ---- P11: gate + fusion -> bY ----
  for (int tok = blk; tok < 2048; tok += 384) {
    size_t rb = (size_t)tok * H;
    float dv0 = b2f(a.bQ[rb + t]), vv0 = b2f(a.bV[rb + t]);
    float dv1 = 0.f, vv1 = 0.f;
    float p = dv0 * a.gate_w[t] + vv0 * a.gate_w[H + t];
    if (t < 256) {
      dv1 = b2f(a.bQ[rb + t + 512]); vv1 = b2f(a.bV[rb + t + 512]);
      p += dv1 * a.gate_w[t + 512] + vv1 * a.gate_w[H + t + 512];
    }
    red[t] = p; __syncthreads();
    for (int st = 256; st; st >>= 1) { if (t < st) red[t] += red[t + st]; __syncthreads(); }
    float g = 1.0f / (1.0f + __expf(-red[0]));
    __syncthreads();
    a.bY[rb + t] = f2b(g * vv0 + (1.0f - g) * dv0);
    if (t < 256) a.bY[rb + t + 512] = f2b(g * vv1 + (1.0f - g) * dv1);
  }
  __threadfence(); grid.sync();

  // ---- P12: nf_pre -> F0 ; final_pre -> F1 ----
  {
    TileW r1 = {a.bY, a.w_nf, NO, NO, a.b_nf, NO, NO, a.F0, NO, H, 0, 0};
    gemm_tile(sA, sB, r1, blk);
    TileW r2 = {a.bY, a.w_final, NO, NO, a.b_final, NO, NO, a.F1, NO, H, 0, 0};
    gemm_tile(sA, sB, r2, blk);
  }
  __threadfence(); grid.sync();

  // ---- P13: out = sigmoid([van, nf_pre]@nf_out) * tanh(final_pre) ----
  for (int tok = blk; tok < 2048; tok += 384) {
    size_t rb = (size_t)tok * H;
    float p = b2f(a.bVan[rb + t]) * a.nf_out_w[t] + a.F0[rb + t] * a.nf_out_w[H + t];
    if (t < 256) {
      p += b2f(a.bVan[rb + t + 512]) * a.nf_out_w[t + 512] + a.F0[rb + t + 512] * a.nf_out_w[H + t + 512];
    }
    red[t] = p; __syncthreads();
    for (int st = 256; st; st >>= 1) { if (t < st) red[t] += red[t + st]; __syncthreads(); }
    float nf = 1.0f / (1.0f + __expf(-red[0]));
    __syncthreads();
    a.out[rb + t] = nf * tanhf(a.F1[rb + t]);
    if (t < 256) a.out[rb + t + 512] = nf * tanhf(a.F1[rb + t + 512]);
  }
}

// ======================= launch =======================
extern "C" void kernel_launch(void* const* d_in, const int* in_sizes, int n_in,
                              void* d_out, int out_size, void* d_ws, size_t ws_size,
                              hipStream_t stream) {
  const float* x        = (const float*)d_in[0];
  const float* y        = (const float*)d_in[1];
  const float* vq_w     = (const float*)d_in[2];
  const float* vq_b     = (const float*)d_in[3];
  const float* vk_w     = (const float*)d_in[4];
  const float* vk_b     = (const float*)d_in[5];
  const float* vv_w     = (const float*)d_in[6];
  const float* vv_b     = (const float*)d_in[7];
  const float* dv_w     = (const float*)d_in[12];
  const float* dv_b     = (const float*)d_in[13];
  const float* van_fc_w = (const float*)d_in[14];
  const float* van_fc_b = (const float*)d_in[15];
  const float* d_theta_w= (const float*)d_in[17];
  const float* WV_w     = (const float*)d_in[19];
  const float* diff_fc_w= (const float*)d_in[20];
  const float* diff_fc_b= (const float*)d_in[21];
  const float* v_gamma_w= (const float*)d_in[22];
  const float* diff_out_w=(const float*)d_in[24];
  const float* diff_out_b=(const float*)d_in[25];
  const float* van_out_w= (const float*)d_in[26];
  const float* van_out_b= (const float*)d_in[27];
  const float* diff_fus_w=(const float*)d_in[28];
  const float* diff_fus_b=(const float*)d_in[29];
  const float* van_fus_w= (const float*)d_in[30];
  const float* van_fus_b= (const float*)d_in[31];
  const float* gate_w   = (const float*)d_in[32];
  const float* nf_w     = (const float*)d_in[33];
  const float* nf_b     = (const float*)d_in[34];
  const float* nf_out_w = (const float*)d_in[35];
  const float* final_w  = (const float*)d_in[36];
  const float* final_b  = (const float*)d_in[37];
  float* out = (float*)d_out;

  u16* wt = (u16*)d_ws;
  const size_t HH_ = (size_t)H * H;
  const size_t HH2 = 2 * HH_;
  size_t woff[14];
  const float* wsrc[14] = {vq_w, vk_w, vv_w, van_fc_w, WV_w, diff_fc_w, diff_fus_w, van_fus_w,
                           nf_w, final_w, d_theta_w, v_gamma_w, diff_out_w, van_out_w};
  int wk[14] = {12,12,12,12,12,12,12,12,12,12, 24,24,24,24};
  size_t o = 0;
  for (int i = 0; i < 14; ++i) { woff[i] = o; o += (i < 10) ? HH_ : HH2; }
  u16* bufs = wt + o;
  u16* bX   = bufs + 0 * TH;
  u16* bY   = bufs + 1 * TH;
  u16* bQ   = bufs + 2 * TH;
  u16* bK   = bufs + 3 * TH;
  u16* bV   = bufs + 4 * TH;
  u16* bVT  = bufs + 5 * TH;
  u16* bVan = bufs + 6 * TH;
  float* F0 = (float*)(bufs + 7 * TH);
  float* F1 = F0 + TH;
  float* sm = F1 + TH;
  float* ybar  = sm;
  float* dvbar = sm + 1536;
  float* c2    = sm + 3072;
  float* part  = sm + 4608;
  float* colp  = sm + 4608 + 12288;
  float* cinv  = colp + 98304;  // after 128x768 partials

  WprepArgs wa;
  int ts = 0;
  for (int i = 0; i < 14; ++i) {
    wa.src[i] = wsrc[i];
    wa.dst[i] = (unsigned)woff[i];
    wa.ktiles[i] = wk[i];
    wa.tstart[i] = ts;
    ts += wk[i] * 12;
  }
  wa.tstart[14] = ts;
  wa.x = x; wa.y = y; wa.bx = bX; wa.by = bY; wa.part = part;
  prep_k<<<ts + 1536 + 48, 256, 0, stream>>>(wa, wt);

  const u16 *wt_vq = wt + woff[0], *wt_vk = wt + woff[1], *wt_vv = wt + woff[2],
            *wt_vanfc = wt + woff[3], *wt_WV = wt + woff[4], *wt_difffc = wt + woff[5],
            *wt_difffus = wt + woff[6], *wt_vanfus = wt + woff[7], *wt_nf = wt + woff[8],
            *wt_final = wt + woff[9], *wt_dtheta = wt + woff[10], *wt_vg = wt + woff[11],
            *wt_diffout = wt + woff[12], *wt_vanout = wt + woff[13];
  Reg RZ = {NO, NO, NO, NO, NO, NO, NO, NO, NO, NO, 0, 0};

  // Launch 2: QKV (+meany2 aux)
  {
    GArgs g;
    g.r0 = {bX, wt_vq, NO, NO, vq_b, NO, bQ, NO, NO, NO, H, 0};
    g.r1 = {bY, wt_vk, NO, NO, vk_b, NO, bK, NO, NO, NO, H, 0};
    g.r2 = {bY, wt_vv, NO, NO, vv_b, NO, NO, bVT, NO, NO, H, 0};
    g.act = 0; g.nx = 36; g.m2part = part; g.m2ybar = ybar;
    bgemm_k<<<dim3(39, 32), 512, 0, stream>>>(g);
  }
  // Launch 3: attention (+gemv1 aux: ybar@dv_w+dv_b -> dvbar)
  mattn_k<<<768, 256, 0, stream>>>(bQ, bK, bVT, bVan, ybar, dv_w, dv_b, dvbar);

  // Launch 4: cooperative mega-kernel (everything else)
  MegaArgs ma;
  ma.bVan = bVan; ma.bX = bX; ma.bY = bY; ma.bQ = bQ; ma.bK = bK; ma.bV = bV;
  ma.F0 = F0; ma.F1 = F1; ma.out = out;
  ma.w_vanfc = wt_vanfc; ma.w_WV = wt_WV; ma.w_dth2 = wt_dtheta + H;
  ma.w_difffc = wt_difffc; ma.w_diffout2 = wt_diffout + H;
  ma.w_vg = wt_vg; ma.w_vg2 = wt_vg + H;
  ma.w_vanout = wt_vanout; ma.w_vanout2 = wt_vanout + H;
  ma.w_difffus = wt_difffus; ma.w_vanfus = wt_vanfus; ma.w_nf = wt_nf; ma.w_final = wt_final;
  ma.b_vanfc = van_fc_b; ma.b_difffc = diff_fc_b; ma.b_vanout = van_out_b;
  ma.b_difffus = diff_fus_b; ma.b_vanfus = van_fus_b; ma.b_nf = nf_b; ma.b_final = final_b;
  ma.dvbar = dvbar; ma.gate_w = gate_w; ma.nf_out_w = nf_out_w;
  ma.g2A = dvbar; ma.g2W = diff_out_w; ma.g2B = diff_out_b; ma.c2 = c2;
  ma.colp = colp; ma.cinv = cinv;
  void* kp[] = {&ma};
  hipError_t ce = hipLaunchCooperativeKernel((const void*)mega_k, dim3(384), dim3(512), kp, 0, stream);

  if (ce != hipSuccess) {
    // ---- fallback: separate-kernel sequence (identical math) ----
    gemv_k<<<384, 256, 0, stream>>>(dvbar, diff_out_w, diff_out_b, c2, 0);
    {
      GArgs g;
      g.r0 = {bVan, wt_vanfc, NO, NO, van_fc_b, NO, bX, NO, NO, NO, H, 0};
      g.r1 = {bVan, wt_WV, NO, NO, NO, NO, bK, NO, NO, NO, H, 0};
      g.r2 = RZ; g.act = 1; g.nx = 24; g.m2part = NO; g.m2ybar = NO;
      bgemm_k<<<dim3(24, 32), 512, 0, stream>>>(g);
    }
    {
      GArgs g;
      g.r0 = {bX, wt_dtheta + H, NO, NO, NO, NO, bY, NO, NO, colp, 2 * H, 0};
      g.r1 = RZ; g.r2 = RZ; g.act = 0; g.nx = 12; g.m2part = NO; g.m2ybar = NO;
      bgemm_k<<<dim3(12, 32), 512, 0, stream>>>(g);
    }
    colsmA_k<<<256, 256, 0, stream>>>(bY, colp, dvbar, NO, bQ);
    {
      GArgs g;
      g.r0 = {bQ, wt_difffc, NO, NO, diff_fc_b, NO, bV, NO, NO, NO, H, 0};
      g.r1 = {bQ, wt_diffout + H, NO, NO, NO, c2, bY, NO, NO, NO, 2 * H, 0};
      g.r2 = RZ; g.act = 1; g.nx = 24; g.m2part = NO; g.m2ybar = NO;
      bgemm_k<<<dim3(24, 32), 512, 0, stream>>>(g);
    }
    {
      GArgs g;
      g.r0 = {bK, wt_vg, bV, wt_vg + H, NO, NO, bX, NO, NO, colp, 2 * H, 2 * H};
      g.r1 = RZ; g.r2 = RZ; g.act = 0; g.nx = 12; g.m2part = NO; g.m2ybar = NO;
      bgemm_k<<<dim3(12, 32), 512, 0, stream>>>(g);
    }
    colsmA_k<<<256, 256, 0, stream>>>(bX, colp, NO, bVan, bX);
    {
      GArgs g;
      g.r0 = {bVan, wt_vanout, bX, wt_vanout + H, van_out_b, NO, bK, NO, NO, NO, 2 * H, 2 * H};
      g.r1 = {bY, wt_difffus, NO, NO, diff_fus_b, NO, bQ, NO, NO, NO, H, 0};
      g.r2 = RZ; g.act = 1; g.nx = 24; g.m2part = NO; g.m2ybar = NO;
      bgemm_k<<<dim3(24, 32), 512, 0, stream>>>(g);
    }
    {
      GArgs g;
      g.r0 = {bK, wt_vanfus, NO, NO, van_fus_b, NO, bV, NO, NO, NO, H, 0};
      g.r1 = RZ; g.r2 = RZ; g.act = 1; g.nx = 12; g.m2part = NO; g.m2ybar = NO;
      bgemm_k<<<dim3(12, 32), 512, 0, stream>>>(g);
    }
    gatefuse_k<<<T, 256, 0, stream>>>(bQ, bV, gate_w, bY);
    {
      GArgs g;
      g.r0 = {bY, wt_nf, NO, NO, nf_b, NO, NO, NO, F0, NO, H, 0};
      g.r1 = {bY, wt_final, NO, NO, final_b, NO, NO, NO, F1, NO, H, 0};
      g.r2 = RZ; g.act = 0; g.nx = 24; g.m2part = NO; g.m2ybar = NO;
      bgemm_k<<<dim3(24, 32), 512, 0, stream>>>(g);
    }
    nffinal_k<<<T, 256, 0, stream>>>(bVan, F0, nf_out_w, F1, out);
  }
}

// Round 13
// 216.479 us; speedup vs baseline: 7.0200x; 7.0200x over previous
//
#include <hip/hip_runtime.h>
#include <hip/hip_bf16.h>
#include <math.h>

#define H 768
#define S 1024
#define BATCH 2
#define T 2048  // BATCH*S
#define TH ((size_t)T * H)
#define NO nullptr

typedef unsigned short u16;
typedef unsigned long long u64;
typedef __attribute__((ext_vector_type(8))) short short8;
typedef __attribute__((ext_vector_type(4))) float f32x4;

__device__ __forceinline__ u16 f2b(float f) {
  __hip_bfloat16 h = __float2bfloat16(f);
  return *reinterpret_cast<u16*>(&h);
}
__device__ __forceinline__ float b2f(u16 u) {
  __hip_bfloat16 h = *reinterpret_cast<__hip_bfloat16*>(&u);
  return __bfloat162float(h);
}
__device__ __forceinline__ void gload16(const u16* g, u16* lds) {
  __builtin_amdgcn_global_load_lds((const __attribute__((address_space(1))) void*)g,
                                   (__attribute__((address_space(3))) void*)lds, 16, 0, 0);
}

// ======================= fused prep: weight transpose + x/y cvt + meany stage1 ===========
struct WprepArgs {
  const float* src[14];
  unsigned dst[14];
  int ktiles[14];
  int tstart[15];
  const float *x, *y;
  u16 *bx, *by;
  float* part;
};
__global__ __launch_bounds__(256) void prep_k(WprepArgs a, u16* __restrict__ wt) {
  __shared__ float sT[64][68];
  int blk = blockIdx.x;
  int t = threadIdx.x;
  int ts = a.tstart[14];
  if (blk >= ts + 1536) {  // meany1: 48 blocks
    int bb = blk - ts - 1536;
    int b = bb / 24, r = bb % 24, cc = r / 8, sc = r % 8;
    int c = cc * 256 + t;
    const float* yp = a.y + (size_t)b * S * H + (size_t)sc * 128 * H + c;
    float s = 0.f;
    for (int j = 0; j < 128; ++j) s += yp[(size_t)j * H];
    a.part[(sc * 2 + b) * H + c] = s;
    return;
  }
  if (blk >= ts) {  // cvt: 1536 blocks (768 x, 768 y)
    int bb = blk - ts;
    const float* src = (bb < 768) ? a.x : a.y;
    u16* dst = (bb < 768) ? a.bx : a.by;
    int i = (bb % 768) * 256 + t;
    float4 va = ((const float4*)src)[2 * i];
    float4 vb = ((const float4*)src)[2 * i + 1];
    u16 tmp[8] = {f2b(va.x), f2b(va.y), f2b(va.z), f2b(va.w), f2b(vb.x), f2b(vb.y), f2b(vb.z), f2b(vb.w)};
    ((uint4*)dst)[i] = *(uint4*)tmp;
    return;
  }
  int mi = 0;
  while (blk >= a.tstart[mi + 1]) ++mi;
  int local = blk - a.tstart[mi];
  int kt = a.ktiles[mi];
  int tn = local / kt, tk = local % kt;
  int K = kt * 64;
  const float* W = a.src[mi];
  u16* D = wt + a.dst[mi];
  int r = t >> 2, c = (t & 3) * 16;
  const float4* srcp = (const float4*)(W + ((size_t)(tk * 64 + r)) * H + tn * 64 + c);
  float4 v0 = srcp[0], v1 = srcp[1], v2 = srcp[2], v3 = srcp[3];
  *(float4*)&sT[r][c] = v0; *(float4*)&sT[r][c + 4] = v1;
  *(float4*)&sT[r][c + 8] = v2; *(float4*)&sT[r][c + 12] = v3;
  __syncthreads();
  int n = t >> 2, kk = (t & 3) * 16;
  u16 tmp[16];
  #pragma unroll
  for (int j = 0; j < 16; ++j) tmp[j] = f2b(sT[kk + j][n]);
  uint4* dst = (uint4*)(D + ((size_t)(tn * 64 + n)) * K + tk * 64 + kk);
  dst[0] = *(uint4*)&tmp[0];
  dst[1] = *(uint4*)&tmp[8];
}

// ======================= multi-region bf16 MFMA GEMM (+ aux blocks) =======================
// 64x64 tile, 8 waves (512 thr), 3-buf LDS, counted vmcnt(2).
// Aux blocks (x >= nx): meany2 (3 blocks, y==0) then gemv (6 x-blocks x 32 y x 8 waves).
struct Reg {
  const u16 *A, *W, *A2, *W2;
  const float *bias, *perbatch;
  u16* Cb; u16* CbT; float* Cf; float* colPart;
  int ldw, ldw2;
};
struct GArgs {
  Reg r0, r1, r2; int act;
  int nx;
  const float* m2part; float* m2ybar;           // aux: meany2
  const float *gvA, *gvW, *gvB; float* gvO;     // aux: gemv (1536 outputs)
};

__global__ __launch_bounds__(512) void bgemm_k(GArgs ga) {
  __shared__ u16 sA[3][64 * 64];
  __shared__ u16 sB[3][64 * 64];
  int t = threadIdx.x;
  int bx = blockIdx.x;
  if (bx >= ga.nx) {
    if (ga.m2part && bx < ga.nx + 3) {  // meany2 aux
      if (blockIdx.y == 0) {
        int idx = (bx - ga.nx) * 512 + t;
        int b = idx / H, c = idx % H;
        float s = 0.f;
        #pragma unroll
        for (int sc = 0; sc < 8; ++sc) s += ga.m2part[(sc * 2 + b) * H + c];
        ga.m2ybar[idx] = s * (1.0f / 1024.0f);
      }
      return;
    }
    if (ga.gvA) {  // gemv aux: gid over 6 x-blocks x 32 y x 8 waves = 1536
      int base = ga.nx + (ga.m2part ? 3 : 0);
      int gid = ((bx - base) * 32 + blockIdx.y) * 8 + (t >> 6);
      int lane = t & 63;
      int b = gid / H, n = gid % H;
      const float* av = ga.gvA + b * H;
      float s = 0.f;
      #pragma unroll
      for (int i = 0; i < 12; ++i) {
        int k = lane + 64 * i;
        s = fmaf(av[k], ga.gvW[(size_t)k * H + n], s);
      }
      #pragma unroll
      for (int off = 32; off; off >>= 1) s += __shfl_xor(s, off);
      if (lane == 0) ga.gvO[gid] = s + (ga.gvB ? ga.gvB[n] : 0.f);
    }
    return;
  }
  int ri = bx / 12;
  Reg R;
  if (ri == 0) R = ga.r0; else if (ri == 1) R = ga.r1; else R = ga.r2;
  int n0 = (bx % 12) * 64;
  int m0 = blockIdx.y * 64;
  int w = t >> 6, l = t & 63, lr = l & 15, lg = l >> 4;
  int wr = (w & 3) * 16, wc = (w >> 2) * 32;

  f32x4 acc[2];
  acc[0] = (f32x4){0.f, 0.f, 0.f, 0.f};
  acc[1] = (f32x4){0.f, 0.f, 0.f, 0.f};

  int NT = R.A2 ? 24 : 12;

  auto stage = [&](int ti) {
    int bi = ti % 3;
    const u16* Aq = (ti < 12) ? R.A : R.A2;
    const u16* Wq = (ti < 12) ? R.W : R.W2;
    int ldwq = (ti < 12) ? R.ldw : R.ldw2;
    int k0 = (ti % 12) * 64;
    int rr = t >> 3, c8 = t & 7;
    gload16(Aq + (size_t)(m0 + rr) * H + k0 + 8 * (c8 ^ (rr & 7)), &sA[bi][0] + t * 8);
    gload16(Wq + (size_t)(n0 + rr) * ldwq + k0 + 8 * (c8 ^ (rr & 7)), &sB[bi][0] + t * 8);
  };

  stage(0);
  stage(1);
  for (int kt = 0; kt < NT; ++kt) {
    if (kt + 1 < NT) asm volatile("s_waitcnt vmcnt(2)" ::: "memory");
    else             asm volatile("s_waitcnt vmcnt(0)" ::: "memory");
    __builtin_amdgcn_s_barrier();
    if (kt + 2 < NT) stage(kt + 2);
    const u16* sAv = &sA[kt % 3][0];
    const u16* sBv = &sB[kt % 3][0];
    __builtin_amdgcn_s_setprio(1);
    #pragma unroll
    for (int kh = 0; kh < 2; ++kh) {
      int arow = wr + lr;
      short8 af = *(const short8*)(sAv + arow * 64 + 8 * ((4 * kh + lg) ^ (arow & 7)));
      #pragma unroll
      for (int ni = 0; ni < 2; ++ni) {
        int brow = wc + 16 * ni + lr;
        short8 bf = *(const short8*)(sBv + brow * 64 + 8 * ((4 * kh + lg) ^ (brow & 7)));
        acc[ni] = __builtin_amdgcn_mfma_f32_16x16x32_bf16(af, bf, acc[ni], 0, 0, 0);
      }
    }
    __builtin_amdgcn_s_setprio(0);
  }

  float ps[2] = {0.f, 0.f};
  #pragma unroll
  for (int ni = 0; ni < 2; ++ni) {
    int col = n0 + wc + 16 * ni + lr;
    u16 tmp4[4];
    #pragma unroll
    for (int reg = 0; reg < 4; ++reg) {
      int row = m0 + wr + lg * 4 + reg;
      int bb = row >> 10;
      float v = acc[ni][reg];
      if (R.bias) v += R.bias[col];
      if (R.perbatch) v += R.perbatch[bb * H + col];
      if (ga.act) v = tanhf(v);
      tmp4[reg] = f2b(v);
      if (R.Cb) R.Cb[(size_t)row * H + col] = tmp4[reg];
      if (R.Cf) R.Cf[(size_t)row * H + col] = v;
      if (R.colPart) ps[ni] += __expf(b2f(tmp4[reg]));
    }
    if (R.CbT) {
      int row0 = m0 + wr + lg * 4;
      int bb = row0 >> 10, tok = row0 & 1023, hh = col >> 6, dd = col & 63;
      *(u64*)&R.CbT[((size_t)((bb * 12 + hh) * 64 + dd)) * 1024 + tok] = *(u64*)tmp4;
    }
  }
  if (R.colPart) {
    #pragma unroll
    for (int ni = 0; ni < 2; ++ni) {
      float p = ps[ni];
      p += __shfl_xor(p, 16);
      p += __shfl_xor(p, 32);
      if (lg == 0) {
        int col = n0 + wc + 16 * ni + lr;
        R.colPart[(size_t)(blockIdx.y * 4 + (w & 3)) * H + col] = p;
      }
    }
  }
}

// ======================= MFMA attention (+ gemv aux blocks >= 384) ==========
__global__ __launch_bounds__(256) void mattn_k(
    const u16* __restrict__ Q, const u16* __restrict__ Kg,
    const u16* __restrict__ VT, u16* __restrict__ O,
    const float* __restrict__ gA, const float* __restrict__ gW,
    const float* __restrict__ gBias, float* __restrict__ gO)
{
  __shared__ u16 sK[3][64 * 64];
  __shared__ u16 sV[3][64 * 64];
  __shared__ u16 sQ[64 * 64];
  __shared__ u16 sP[4 * 16 * 64];
  int t = threadIdx.x;
  if ((int)blockIdx.x >= 384) {  // aux: gemv (ybar @ dv_w + dv_b -> dvbar)
    int gid = ((int)blockIdx.x - 384) * 4 + (t >> 6);
    int lane = t & 63;
    int b = gid / H, n = gid % H;
    const float* av = gA + b * H;
    float s = 0.f;
    #pragma unroll
    for (int i = 0; i < 12; ++i) {
      int k = lane + 64 * i;
      s = fmaf(av[k], gW[(size_t)k * H + n], s);
    }
    #pragma unroll
    for (int off = 32; off; off >>= 1) s += __shfl_xor(s, off);
    if (lane == 0) gO[gid] = s + gBias[n];
    return;
  }
  int w = t >> 6, l = t & 63, lr = l & 15, lg = l >> 4;
  int blk = blockIdx.x;
  int b = blk / 192; int rem = blk % 192; int h = rem / 16; int q0 = (rem % 16) * 64;

  #pragma unroll
  for (int i = 0; i < 2; ++i) {
    int id = t + i * 256; int r = id >> 3, c = id & 7;
    uint4 v = *(const uint4*)(Q + ((size_t)(b * 1024 + q0 + r)) * H + h * 64 + 8 * c);
    *(uint4*)(&sQ[0] + r * 64 + 8 * (c ^ (r & 7))) = v;
  }

  auto stageKV = [&](int ti) {
    int bi = ti % 3;
    int kv0 = ti * 64;
    #pragma unroll
    for (int ii = 0; ii < 2; ++ii) {
      int chunk = w * 128 + ii * 64 + l;
      int rr = chunk >> 3, c8 = chunk & 7;
      gload16(Kg + ((size_t)(b * 1024 + kv0 + rr)) * H + h * 64 + 8 * (c8 ^ (rr & 7)),
              &sK[bi][0] + (w * 128 + ii * 64) * 8);
      gload16(VT + ((size_t)((b * 12 + h) * 64 + rr)) * 1024 + kv0 + 8 * (c8 ^ (rr & 7)),
              &sV[bi][0] + (w * 128 + ii * 64) * 8);
    }
  };

  stageKV(0);
  stageKV(1);
  asm volatile("s_waitcnt lgkmcnt(0)" ::: "memory");
  __builtin_amdgcn_s_barrier();
  short8 qreg[2];
  #pragma unroll
  for (int kh = 0; kh < 2; ++kh) {
    int qrow = 16 * w + lr;
    qreg[kh] = *(const short8*)(&sQ[0] + qrow * 64 + 8 * ((4 * kh + lg) ^ (qrow & 7)));
  }

  f32x4 oacc[4];
  #pragma unroll
  for (int i = 0; i < 4; ++i) oacc[i] = (f32x4){0.f, 0.f, 0.f, 0.f};
  float lsum = 0.f;

  for (int kt = 0; kt < 16; ++kt) {
    if (kt + 1 < 16) asm volatile("s_waitcnt vmcnt(4)" ::: "memory");
    else             asm volatile("s_waitcnt vmcnt(0)" ::: "memory");
    __builtin_amdgcn_s_barrier();
    if (kt + 2 < 16) stageKV(kt + 2);
    const u16* sKv = &sK[kt % 3][0];
    const u16* sVv = &sV[kt % 3][0];

    f32x4 sacc[4];
    #pragma unroll
    for (int i = 0; i < 4; ++i) sacc[i] = (f32x4){0.f, 0.f, 0.f, 0.f};
    __builtin_amdgcn_s_setprio(1);
    #pragma unroll
    for (int kh = 0; kh < 2; ++kh) {
      #pragma unroll
      for (int ns = 0; ns < 4; ++ns) {
        int krow = 16 * ns + lr;
        short8 kf = *(const short8*)(sKv + krow * 64 + 8 * ((4 * kh + lg) ^ (krow & 7)));
        sacc[ns] = __builtin_amdgcn_mfma_f32_16x16x32_bf16(kf, qreg[kh], sacc[ns], 0, 0, 0);
      }
    }
    __builtin_amdgcn_s_setprio(0);

    #pragma unroll
    for (int ns = 0; ns < 4; ++ns) {
      u16 t4[4];
      #pragma unroll
      for (int reg = 0; reg < 4; ++reg) {
        float p = __expf(sacc[ns][reg] * 0.125f);
        lsum += p;
        t4[reg] = f2b(p);
      }
      unsigned byteoff = (unsigned)(w * 2048 + lr * 128 + (((16 * ns + lg * 4) * 2) ^ ((lr & 7) << 4)));
      *(u64*)((char*)sP + byteoff) = *(u64*)t4;
    }

    __builtin_amdgcn_s_setprio(1);
    #pragma unroll
    for (int kh = 0; kh < 2; ++kh) {
      short8 pf = *(const short8*)((char*)sP + w * 2048 + lr * 128 + (((4 * kh + lg) << 4) ^ ((lr & 7) << 4)));
      #pragma unroll
      for (int ds = 0; ds < 4; ++ds) {
        int vrow = 16 * ds + lr;
        short8 vf = *(const short8*)(sVv + vrow * 64 + 8 * ((4 * kh + lg) ^ (vrow & 7)));
        oacc[ds] = __builtin_amdgcn_mfma_f32_16x16x32_bf16(pf, vf, oacc[ds], 0, 0, 0);
      }
    }
    __builtin_amdgcn_s_setprio(0);
  }

  lsum += __shfl_xor(lsum, 16);
  lsum += __shfl_xor(lsum, 32);
  float linv = 1.0f / lsum;
  #pragma unroll
  for (int r = 0; r < 4; ++r) {
    float inv = __shfl(linv, lg * 4 + r);
    int qrow = q0 + 16 * w + lg * 4 + r;
    #pragma unroll
    for (int ds = 0; ds < 4; ++ds) {
      int d = 16 * ds + lr;
      O[((size_t)(b * 1024 + qrow)) * H + h * 64 + d] = f2b(oacc[ds][r] * inv);
    }
  }
}

// ======================= axis-1 softmax apply ===========
__global__ __launch_bounds__(256) void colsmA_k(
    const u16* __restrict__ Z, const float* __restrict__ part,
    const float* __restrict__ mulvec, const u16* __restrict__ mulmat, u16* __restrict__ O) {
  int blk = blockIdx.x;
  int b = blk >> 7, sc = blk & 127;
  int t = threadIdx.x;
  float s0 = 0.f, s1 = 0.f, s2 = 0.f;
  for (int i = b * 64; i < b * 64 + 64; ++i) {
    const float* pp = part + (size_t)i * H;
    s0 += pp[t]; s1 += pp[t + 256]; s2 += pp[t + 512];
  }
  float i0 = 1.0f / s0, i1 = 1.0f / s1, i2 = 1.0f / s2;
  size_t base = ((size_t)(b * 1024 + sc * 8)) * H;
  float m0 = 0.f, m1 = 0.f, m2 = 0.f;
  if (mulvec) { m0 = mulvec[b * H + t]; m1 = mulvec[b * H + t + 256]; m2 = mulvec[b * H + t + 512]; }
  #pragma unroll
  for (int j = 0; j < 8; ++j) {
    size_t row = base + (size_t)j * H;
    float e0 = __expf(b2f(Z[row + t]));
    float e1 = __expf(b2f(Z[row + t + 256]));
    float e2 = __expf(b2f(Z[row + t + 512]));
    float u0 = mulmat ? b2f(mulmat[row + t]) : m0;
    float u1 = mulmat ? b2f(mulmat[row + t + 256]) : m1;
    float u2 = mulmat ? b2f(mulmat[row + t + 512]) : m2;
    O[row + t] = f2b(u0 * e0 * i0);
    O[row + t + 256] = f2b(u1 * e1 * i1);
    O[row + t + 512] = f2b(u2 * e2 * i2);
  }
}

// ======================= gate + fusion =======================
__global__ __launch_bounds__(256) void gatefuse_k(
    const u16* __restrict__ DF, const u16* __restrict__ VF,
    const float* __restrict__ GW, u16* __restrict__ FU)
{
  __shared__ float red[256];
  int tok = blockIdx.x;
  int t = threadIdx.x;
  const u16* df = DF + (size_t)tok * H;
  const u16* vf = VF + (size_t)tok * H;
  float dv[3], vv[3];
  float p = 0.f;
  #pragma unroll
  for (int i = 0; i < 3; ++i) {
    int c = t + i * 256;
    dv[i] = b2f(df[c]); vv[i] = b2f(vf[c]);
    p = fmaf(dv[i], GW[c], p);
    p = fmaf(vv[i], GW[H + c], p);
  }
  red[t] = p; __syncthreads();
  for (int st = 128; st; st >>= 1) { if (t < st) red[t] += red[t + st]; __syncthreads(); }
  float g = 1.0f / (1.0f + __expf(-red[0]));
  u16* fu = FU + (size_t)tok * H;
  #pragma unroll
  for (int i = 0; i < 3; ++i) {
    int c = t + i * 256;
    fu[c] = f2b(g * vv[i] + (1.0f - g) * dv[i]);
  }
}

// ======================= nf + final output =======================
__global__ __launch_bounds__(256) void nffinal_k(
    const u16* __restrict__ VAN, const float* __restrict__ NP,
    const float* __restrict__ NW, const float* __restrict__ FP,
    float* __restrict__ OUT)
{
  __shared__ float red[256];
  int tok = blockIdx.x;
  int t = threadIdx.x;
  const u16* va = VAN + (size_t)tok * H;
  const float* np = NP + (size_t)tok * H;
  float p = 0.f;
  #pragma unroll
  for (int i = 0; i < 3; ++i) {
    int c = t + i * 256;
    p = fmaf(b2f(va[c]), NW[c], p);
    p = fmaf(np[c], NW[H + c], p);
  }
  red[t] = p; __syncthreads();
  for (int st = 128; st; st >>= 1) { if (t < st) red[t] += red[t + st]; __syncthreads(); }
  float nf = 1.0f / (1.0f + __expf(-red[0]));
  const float* fp = FP + (size_t)tok * H;
  float* o = OUT + (size_t)tok * H;
  #pragma unroll
  for (int i = 0; i < 3; ++i) {
    int c = t + i * 256;
    o[c] = nf * tanhf(fp[c]);
  }
}

// ======================= launch =======================
extern "C" void kernel_launch(void* const* d_in, const int* in_sizes, int n_in,
                              void* d_out, int out_size, void* d_ws, size_t ws_size,
                              hipStream_t stream) {
  const float* x        = (const float*)d_in[0];
  const float* y        = (const float*)d_in[1];
  const float* vq_w     = (const float*)d_in[2];
  const float* vq_b     = (const float*)d_in[3];
  const float* vk_w     = (const float*)d_in[4];
  const float* vk_b     = (const float*)d_in[5];
  const float* vv_w     = (const float*)d_in[6];
  const float* vv_b     = (const float*)d_in[7];
  const float* dv_w     = (const float*)d_in[12];
  const float* dv_b     = (const float*)d_in[13];
  const float* van_fc_w = (const float*)d_in[14];
  const float* van_fc_b = (const float*)d_in[15];
  const float* d_theta_w= (const float*)d_in[17];
  const float* WV_w     = (const float*)d_in[19];
  const float* diff_fc_w= (const float*)d_in[20];
  const float* diff_fc_b= (const float*)d_in[21];
  const float* v_gamma_w= (const float*)d_in[22];
  const float* diff_out_w=(const float*)d_in[24];
  const float* diff_out_b=(const float*)d_in[25];
  const float* van_out_w= (const float*)d_in[26];
  const float* van_out_b= (const float*)d_in[27];
  const float* diff_fus_w=(const float*)d_in[28];
  const float* diff_fus_b=(const float*)d_in[29];
  const float* van_fus_w= (const float*)d_in[30];
  const float* van_fus_b= (const float*)d_in[31];
  const float* gate_w   = (const float*)d_in[32];
  const float* nf_w     = (const float*)d_in[33];
  const float* nf_b     = (const float*)d_in[34];
  const float* nf_out_w = (const float*)d_in[35];
  const float* final_w  = (const float*)d_in[36];
  const float* final_b  = (const float*)d_in[37];
  float* out = (float*)d_out;

  u16* wt = (u16*)d_ws;
  const size_t HH_ = (size_t)H * H;
  const size_t HH2 = 2 * HH_;
  size_t woff[14];
  const float* wsrc[14] = {vq_w, vk_w, vv_w, van_fc_w, WV_w, diff_fc_w, diff_fus_w, van_fus_w,
                           nf_w, final_w, d_theta_w, v_gamma_w, diff_out_w, van_out_w};
  int wk[14] = {12,12,12,12,12,12,12,12,12,12, 24,24,24,24};
  size_t o = 0;
  for (int i = 0; i < 14; ++i) { woff[i] = o; o += (i < 10) ? HH_ : HH2; }
  u16* bufs = wt + o;
  u16* bX   = bufs + 0 * TH;
  u16* bY   = bufs + 1 * TH;
  u16* bQ   = bufs + 2 * TH;
  u16* bK   = bufs + 3 * TH;
  u16* bV   = bufs + 4 * TH;
  u16* bVT  = bufs + 5 * TH;
  u16* bVan = bufs + 6 * TH;
  float* F0 = (float*)(bufs + 7 * TH);
  float* F1 = F0 + TH;
  float* sm = F1 + TH;
  float* ybar  = sm;
  float* dvbar = sm + 1536;
  float* c2    = sm + 3072;
  float* part  = sm + 4608;
  float* colp  = sm + 4608 + 12288;   // 128 x 768 column-exp partials

  WprepArgs wa;
  int ts = 0;
  for (int i = 0; i < 14; ++i) {
    wa.src[i] = wsrc[i];
    wa.dst[i] = (unsigned)woff[i];
    wa.ktiles[i] = wk[i];
    wa.tstart[i] = ts;
    ts += wk[i] * 12;
  }
  wa.tstart[14] = ts;
  wa.x = x; wa.y = y; wa.bx = bX; wa.by = bY; wa.part = part;
  prep_k<<<ts + 1536 + 48, 256, 0, stream>>>(wa, wt);

  const u16 *wt_vq = wt + woff[0], *wt_vk = wt + woff[1], *wt_vv = wt + woff[2],
            *wt_vanfc = wt + woff[3], *wt_WV = wt + woff[4], *wt_difffc = wt + woff[5],
            *wt_difffus = wt + woff[6], *wt_vanfus = wt + woff[7], *wt_nf = wt + woff[8],
            *wt_final = wt + woff[9], *wt_dtheta = wt + woff[10], *wt_vg = wt + woff[11],
            *wt_diffout = wt + woff[12], *wt_vanout = wt + woff[13];
  Reg RZ = {NO, NO, NO, NO, NO, NO, NO, NO, NO, NO, 0, 0};

  // L2: QKV (+meany2 aux)
  {
    GArgs g;
    g.r0 = {bX, wt_vq, NO, NO, vq_b, NO, bQ, NO, NO, NO, H, 0};
    g.r1 = {bY, wt_vk, NO, NO, vk_b, NO, bK, NO, NO, NO, H, 0};
    g.r2 = {bY, wt_vv, NO, NO, vv_b, NO, NO, bVT, NO, NO, H, 0};
    g.act = 0; g.nx = 36; g.m2part = part; g.m2ybar = ybar;
    g.gvA = NO; g.gvW = NO; g.gvB = NO; g.gvO = NO;
    bgemm_k<<<dim3(39, 32), 512, 0, stream>>>(g);
  }
  // L3: attention (+gemv1 aux: dvbar = ybar@dv_w + dv_b)
  mattn_k<<<768, 256, 0, stream>>>(bQ, bK, bVT, bVan, ybar, dv_w, dv_b, dvbar);

  // L4: tv (->bX), gA (->bK)  (+gemv2 aux: c2 = dvbar@diff_out_w(top) + diff_out_b)
  {
    GArgs g;
    g.r0 = {bVan, wt_vanfc, NO, NO, van_fc_b, NO, bX, NO, NO, NO, H, 0};
    g.r1 = {bVan, wt_WV, NO, NO, NO, NO, bK, NO, NO, NO, H, 0};
    g.r2 = RZ;
    g.act = 1; g.nx = 24; g.m2part = NO; g.m2ybar = NO;
    g.gvA = dvbar; g.gvW = diff_out_w; g.gvB = diff_out_b; g.gvO = c2;
    bgemm_k<<<dim3(30, 32), 512, 0, stream>>>(g);
  }
  // L5: z1 = tv@dth2 -> bY (+colPart)
  {
    GArgs g;
    g.r0 = {bX, wt_dtheta + H, NO, NO, NO, NO, bY, NO, NO, colp, 2 * H, 0};
    g.r1 = RZ; g.r2 = RZ;
    g.act = 0; g.nx = 12; g.m2part = NO; g.m2ybar = NO;
    g.gvA = NO; g.gvW = NO; g.gvB = NO; g.gvO = NO;
    bgemm_k<<<dim3(12, 32), 512, 0, stream>>>(g);
  }
  // L6: d_theta = dvbar * softmax(z1) -> bQ
  colsmA_k<<<256, 256, 0, stream>>>(bY, colp, dvbar, NO, bQ);
  // L7: gB (->bV), diff_out (->bY)
  {
    GArgs g;
    g.r0 = {bQ, wt_difffc, NO, NO, diff_fc_b, NO, bV, NO, NO, NO, H, 0};
    g.r1 = {bQ, wt_diffout + H, NO, NO, NO, c2, bY, NO, NO, NO, 2 * H, 0};
    g.r2 = RZ;
    g.act = 1; g.nx = 24; g.m2part = NO; g.m2ybar = NO;
    g.gvA = NO; g.gvW = NO; g.gvB = NO; g.gvO = NO;
    bgemm_k<<<dim3(24, 32), 512, 0, stream>>>(g);
  }
  // L8: z2 = gA@vg1 + gB@vg2 -> bX (+colPart)
  {
    GArgs g;
    g.r0 = {bK, wt_vg, bV, wt_vg + H, NO, NO, bX, NO, NO, colp, 2 * H, 2 * H};
    g.r1 = RZ; g.r2 = RZ;
    g.act = 0; g.nx = 12; g.m2part = NO; g.m2ybar = NO;
    g.gvA = NO; g.gvW = NO; g.gvB = NO; g.gvO = NO;
    bgemm_k<<<dim3(12, 32), 512, 0, stream>>>(g);
  }
  // L9: a_gamma = van * softmax(z2) -> bX in place
  colsmA_k<<<256, 256, 0, stream>>>(bX, colp, NO, bVan, bX);
  // L10: van_out (->bK), diff_fusion (->bQ)
  {
    GArgs g;
    g.r0 = {bVan, wt_vanout, bX, wt_vanout + H, van_out_b, NO, bK, NO, NO, NO, 2 * H, 2 * H};
    g.r1 = {bY, wt_difffus, NO, NO, diff_fus_b, NO, bQ, NO, NO, NO, H, 0};
    g.r2 = RZ;
    g.act = 1; g.nx = 24; g.m2part = NO; g.m2ybar = NO;
    g.gvA = NO; g.gvW = NO; g.gvB = NO; g.gvO = NO;
    bgemm_k<<<dim3(24, 32), 512, 0, stream>>>(g);
  }
  // L11: van_fusion -> bV
  {
    GArgs g;
    g.r0 = {bK, wt_vanfus, NO, NO, van_fus_b, NO, bV, NO, NO, NO, H, 0};
    g.r1 = RZ; g.r2 = RZ;
    g.act = 1; g.nx = 12; g.m2part = NO; g.m2ybar = NO;
    g.gvA = NO; g.gvW = NO; g.gvB = NO; g.gvO = NO;
    bgemm_k<<<dim3(12, 32), 512, 0, stream>>>(g);
  }
  // L12: fusion -> bY
  gatefuse_k<<<T, 256, 0, stream>>>(bQ, bV, gate_w, bY);
  // L13: nf_pre -> F0 ; final_pre -> F1
  {
    GArgs g;
    g.r0 = {bY, wt_nf, NO, NO, nf_b, NO, NO, NO, F0, NO, H, 0};
    g.r1 = {bY, wt_final, NO, NO, final_b, NO, NO, NO, F1, NO, H, 0};
    g.r2 = RZ;
    g.act = 0; g.nx = 24; g.m2part = NO; g.m2ybar = NO;
    g.gvA = NO; g.gvW = NO; g.gvB = NO; g.gvO = NO;
    bgemm_k<<<dim3(24, 32), 512, 0, stream>>>(g);
  }
  // L14: out
  nffinal_k<<<T, 256, 0, stream>>>(bVan, F0, nf_out_w, F1, out);
}